// Round 1
// baseline (3418.832 us; speedup 1.0000x reference)
//
#include <hip/hip_runtime.h>
#include <cstdint>
#include <cstdio>

// ---------------- device helpers ----------------

// order-preserving float<->uint transform for atomicMax on signed floats
__device__ __forceinline__ unsigned f2o(float f) {
    unsigned u = __float_as_uint(f);
    return (u & 0x80000000u) ? ~u : (u | 0x80000000u);
}
__device__ __forceinline__ float o2f(unsigned u) {
    return (u & 0x80000000u) ? __uint_as_float(u ^ 0x80000000u) : __uint_as_float(~u);
}

struct Coords { int xi, yi, zi; };

// EXACT replication of reference quantization:
//   idx = (col - lim0) / (lim1 - lim0) * float(size)  (all f32 ops, truncating cast)
__device__ __forceinline__ Coords quantc(float x, float y, float z, float sx, float sy, float sz) {
    Coords c;
    c.xi = (int)(((x - 0.0f)    / 51.2f) * sx);
    c.yi = (int)(((y - (-25.6f)) / 51.2f) * sy);
    c.zi = (int)(((z - (-2.0f))  / 6.4f)  * sz);
    return c;
}

__device__ __forceinline__ int batch_of(int i, const int* __restrict__ ind, int B) {
    int bt = 0;
    for (int b = 1; b < B; ++b) if (i >= ind[b]) bt = b;
    return bt;
}

// VFE per-point features for one scale.
// x[16] = (feat@W.T + b) * (mean@Ww.T + wb);  mean6 out = [mm, gmm]
__device__ __forceinline__ void compute_x16(
    float px, float py, float pz, float pw,
    float mx_, float my_, float mz_, Coords c,
    const float* __restrict__ W, const float* __restrict__ Bv,
    const float* __restrict__ Ww, const float* __restrict__ Wb,
    float* __restrict__ x, float* __restrict__ mean6) {
    // gridmean uses fixed GM=0.2, MINS=(0,-25.6,-2), OFFSET=0.5 for BOTH scales (as in reference)
    float gx = px - (((float)c.xi + 0.5f) * 0.2f + 0.0f);
    float gy = py - (((float)c.yi + 0.5f) * 0.2f + (-25.6f));
    float gz = pz - (((float)c.zi + 0.5f) * 0.2f + (-2.0f));
    float mmx = px - mx_, mmy = py - my_, mmz = pz - mz_;
    float feat[10] = {px, py, pz, pw, mmx, mmy, mmz, gx, gy, gz};
    float mean[6]  = {mmx, mmy, mmz, gx, gy, gz};
#pragma unroll
    for (int j = 0; j < 6; ++j) mean6[j] = mean[j];
#pragma unroll
    for (int o = 0; o < 16; ++o) {
        float a = Bv[o];
#pragma unroll
        for (int j = 0; j < 10; ++j) a += feat[j] * W[o * 10 + j];
        float g = Wb[o];
#pragma unroll
        for (int j = 0; j < 6; ++j) g += mean[j] * Ww[o * 6 + j];
        x[o] = a * g;
    }
}

// ---------------- kernels ----------------

// P1: mark occupied voxels in bitmasks (both scales)
__global__ __launch_bounds__(256) void k_bits(
    const float4* __restrict__ pc, const int* __restrict__ ind, int B, int n,
    unsigned* __restrict__ mask05, unsigned* __restrict__ mask1) {
    int i = blockIdx.x * 256 + threadIdx.x;
    if (i >= n) return;
    float4 p = pc[i];
    int bt = batch_of(i, ind, B);
    Coords c05 = quantc(p.x, p.y, p.z, 512.f, 512.f, 64.f);
    Coords c1  = quantc(p.x, p.y, p.z, 256.f, 256.f, 32.f);
    int lid05 = ((bt * 512 + c05.xi) * 512 + c05.yi) * 64 + c05.zi;
    int lid1  = ((bt * 256 + c1.xi)  * 256 + c1.yi)  * 32 + c1.zi;
    atomicOr(&mask05[lid05 >> 5], 1u << (lid05 & 31));
    atomicOr(&mask1[lid1 >> 5],  1u << (lid1 & 31));
}

// S1: per-2048-word chunk popcount sums
__global__ __launch_bounds__(256) void k_chunk(
    const unsigned* __restrict__ mask, unsigned* __restrict__ bsum, int nWords) {
    int t = threadIdx.x;
    int base = blockIdx.x * 2048 + t;
    unsigned tot = 0;
#pragma unroll
    for (int k = 0; k < 8; ++k) {
        int w = base + k * 256;
        if (w < nWords) tot += __popc(mask[w]);
    }
    __shared__ unsigned s[256];
    s[t] = tot;
    __syncthreads();
    for (int off = 128; off > 0; off >>= 1) {
        if (t < off) s[t] += s[t + off];
        __syncthreads();
    }
    if (t == 0) bsum[blockIdx.x] = s[0];
}

// S2: single-block exclusive scan of chunk sums (supports up to 2048*ipt chunks); writes total
__global__ __launch_bounds__(1024) void k_scan(
    const unsigned* __restrict__ bsum, unsigned* __restrict__ bpref,
    unsigned* __restrict__ Uout, int nB) {
    __shared__ unsigned s[1024];
    int t = threadIdx.x;
    int ipt = (nB + 1023) >> 10;
    unsigned tot = 0;
    for (int k = 0; k < ipt; ++k) {
        int e = t * ipt + k;
        if (e < nB) tot += bsum[e];
    }
    s[t] = tot;
    __syncthreads();
    for (int off = 1; off < 1024; off <<= 1) {
        unsigned v = 0;
        if (t >= off) v = s[t - off];
        __syncthreads();
        if (t >= off) s[t] += v;
        __syncthreads();
    }
    unsigned run = s[t] - tot;  // exclusive
    for (int k = 0; k < ipt; ++k) {
        int e = t * ipt + k;
        if (e < nB) { bpref[e] = run; run += bsum[e]; }
    }
    if (t == 1023 && Uout) *Uout = s[1023];
}

// S3: per-word exclusive popcount prefix
__global__ __launch_bounds__(256) void k_wpref(
    const unsigned* __restrict__ mask, const unsigned* __restrict__ bpref,
    unsigned* __restrict__ wpref, int nWords) {
    int t = threadIdx.x;
    int base = blockIdx.x * 2048 + t * 8;
    unsigned p[8];
    unsigned tot = 0;
#pragma unroll
    for (int k = 0; k < 8; ++k) {
        int w = base + k;
        p[k] = (w < nWords) ? __popc(mask[w]) : 0u;
        tot += p[k];
    }
    __shared__ unsigned s[256];
    s[t] = tot;
    __syncthreads();
    for (int off = 1; off < 256; off <<= 1) {
        unsigned v = 0;
        if (t >= off) v = s[t - off];
        __syncthreads();
        if (t >= off) s[t] += v;
        __syncthreads();
    }
    unsigned run = bpref[blockIdx.x] + (s[t] - tot);
#pragma unroll
    for (int k = 0; k < 8; ++k) {
        int w = base + k;
        if (w < nWords) { wpref[w] = run; run += p[k]; }
    }
}

// P3: compute inv (rank) per point, accumulate per-voxel count & xyz sums,
//     scatter coords1 and inv1 into d_out (as float-encoded ints)
__global__ __launch_bounds__(256) void k_rank(
    const float4* __restrict__ pc, const int* __restrict__ ind, int B, int n,
    const unsigned* __restrict__ mask05, const unsigned* __restrict__ wp05,
    const unsigned* __restrict__ mask1, const unsigned* __restrict__ wp1,
    unsigned* __restrict__ inv05, unsigned* __restrict__ inv1,
    unsigned* __restrict__ cnt05, float* __restrict__ s05x, float* __restrict__ s05y, float* __restrict__ s05z,
    unsigned* __restrict__ cnt1, float* __restrict__ s1x, float* __restrict__ s1y, float* __restrict__ s1z,
    float* __restrict__ outCoord, float* __restrict__ outInv) {
    int i = blockIdx.x * 256 + threadIdx.x;
    if (i >= n) return;
    float4 p = pc[i];
    int bt = batch_of(i, ind, B);
    Coords c05 = quantc(p.x, p.y, p.z, 512.f, 512.f, 64.f);
    Coords c1  = quantc(p.x, p.y, p.z, 256.f, 256.f, 32.f);
    int lid05 = ((bt * 512 + c05.xi) * 512 + c05.yi) * 64 + c05.zi;
    int lid1  = ((bt * 256 + c1.xi)  * 256 + c1.yi)  * 32 + c1.zi;

    unsigned w = (unsigned)lid05 >> 5, b = (unsigned)lid05 & 31u;
    unsigned r05 = wp05[w] + __popc(mask05[w] & ((1u << b) - 1u));
    w = (unsigned)lid1 >> 5; b = (unsigned)lid1 & 31u;
    unsigned r1 = wp1[w] + __popc(mask1[w] & ((1u << b) - 1u));

    inv05[i] = r05;
    inv1[i] = r1;
    outInv[i] = (float)r1;
    ((float4*)outCoord)[r1] = make_float4((float)bt, (float)c1.xi, (float)c1.yi, (float)c1.zi);

    atomicAdd(&cnt05[r05], 1u);
    atomicAdd(&s05x[r05], p.x);
    atomicAdd(&s05y[r05], p.y);
    atomicAdd(&s05z[r05], p.z);
    atomicAdd(&cnt1[r1], 1u);
    atomicAdd(&s1x[r1], p.x);
    atomicAdd(&s1y[r1], p.y);
    atomicAdd(&s1z[r1], p.z);
}

// P4: per-point VFE x[16] for both scales, atomicMax into per-voxel mx arrays
__global__ __launch_bounds__(256) void k_vfemax(
    const float4* __restrict__ pc, const int* __restrict__ ind, int B, int n,
    const unsigned* __restrict__ inv05, const unsigned* __restrict__ inv1,
    const unsigned* __restrict__ cnt05, const float* __restrict__ s05x, const float* __restrict__ s05y, const float* __restrict__ s05z,
    const unsigned* __restrict__ cnt1, const float* __restrict__ s1x, const float* __restrict__ s1y, const float* __restrict__ s1z,
    unsigned* __restrict__ mx05, unsigned* __restrict__ mx1,
    const float* __restrict__ w05, const float* __restrict__ b05,
    const float* __restrict__ ww05, const float* __restrict__ wb05,
    const float* __restrict__ w1g, const float* __restrict__ b1g,
    const float* __restrict__ ww1, const float* __restrict__ wb1) {
    int i = blockIdx.x * 256 + threadIdx.x;
    if (i >= n) return;
    float4 p = pc[i];
    int bt = batch_of(i, ind, B);
    unsigned r05 = inv05[i], r1 = inv1[i];
    float mean6[6];
    {
        float c = fmaxf((float)cnt05[r05], 1.0f);
        float mx_ = s05x[r05] / c, my_ = s05y[r05] / c, mz_ = s05z[r05] / c;
        Coords cc = quantc(p.x, p.y, p.z, 512.f, 512.f, 64.f);
        float x[16];
        compute_x16(p.x, p.y, p.z, p.w, mx_, my_, mz_, cc, w05, b05, ww05, wb05, x, mean6);
#pragma unroll
        for (int o = 0; o < 16; ++o) atomicMax(&mx05[(size_t)r05 * 16 + o], f2o(x[o]));
    }
    {
        float c = fmaxf((float)cnt1[r1], 1.0f);
        float mx_ = s1x[r1] / c, my_ = s1y[r1] / c, mz_ = s1z[r1] / c;
        Coords cc = quantc(p.x, p.y, p.z, 256.f, 256.f, 32.f);
        float x[16];
        compute_x16(p.x, p.y, p.z, p.w, mx_, my_, mz_, cc, w1g, b1g, ww1, wb1, x, mean6);
#pragma unroll
        for (int o = 0; o < 16; ++o) atomicMax(&mx1[(size_t)r1 * 16 + o], f2o(x[o]));
    }
    (void)bt;
}

// P5: full feature pipeline + atomicMax of agg into d_out maxf region (uint-transformed)
__global__ __launch_bounds__(256) void k_agg(
    const float4* __restrict__ pc, const int* __restrict__ ind, int B, int n,
    const unsigned* __restrict__ inv05, const unsigned* __restrict__ inv1,
    const unsigned* __restrict__ cnt05, const float* __restrict__ s05x, const float* __restrict__ s05y, const float* __restrict__ s05z,
    const unsigned* __restrict__ cnt1, const float* __restrict__ s1x, const float* __restrict__ s1y, const float* __restrict__ s1z,
    const unsigned* __restrict__ mx05, const unsigned* __restrict__ mx1,
    const float* __restrict__ w05, const float* __restrict__ b05,
    const float* __restrict__ ww05, const float* __restrict__ wb05,
    const float* __restrict__ w1g, const float* __restrict__ b1g,
    const float* __restrict__ ww1, const float* __restrict__ wb1,
    const float* __restrict__ am_w, const float* __restrict__ am_b,
    const float* __restrict__ at_w, const float* __restrict__ at_b,
    const float* __restrict__ af_w, const float* __restrict__ af_b,
    unsigned* __restrict__ outMax) {
    int i = blockIdx.x * 256 + threadIdx.x;
    if (i >= n) return;
    float4 p = pc[i];
    unsigned r05 = inv05[i], r1 = inv1[i];

    float cat[64];
    float mean6[6], dummy6[6];
    {
        float c = fmaxf((float)cnt05[r05], 1.0f);
        float mx_ = s05x[r05] / c, my_ = s05y[r05] / c, mz_ = s05z[r05] / c;
        Coords cc = quantc(p.x, p.y, p.z, 512.f, 512.f, 64.f);
        compute_x16(p.x, p.y, p.z, p.w, mx_, my_, mz_, cc, w05, b05, ww05, wb05, &cat[0], dummy6);
#pragma unroll
        for (int k = 0; k < 16; ++k) cat[16 + k] = o2f(mx05[(size_t)r05 * 16 + k]);
    }
    {
        float c = fmaxf((float)cnt1[r1], 1.0f);
        float mx_ = s1x[r1] / c, my_ = s1y[r1] / c, mz_ = s1z[r1] / c;
        Coords cc = quantc(p.x, p.y, p.z, 256.f, 256.f, 32.f);
        compute_x16(p.x, p.y, p.z, p.w, mx_, my_, mz_, cc, w1g, b1g, ww1, wb1, &cat[32], mean6);
#pragma unroll
        for (int k = 0; k < 16; ++k) cat[48 + k] = o2f(mx1[(size_t)r1 * 16 + k]);
    }

    float h[32];
#pragma unroll
    for (int o = 0; o < 32; ++o) {
        float am = am_b[o];
#pragma unroll
        for (int j = 0; j < 6; ++j) am += mean6[j] * am_w[o * 6 + j];
        float at = at_b[o];
#pragma unroll
        for (int j = 0; j < 64; ++j) at += cat[j] * at_w[o * 64 + j];
        h[o] = fmaxf(am, 0.0f) * fmaxf(at, 0.0f);
    }
#pragma unroll
    for (int o = 0; o < 32; ++o) {
        float v = af_b[o];
#pragma unroll
        for (int j = 0; j < 32; ++j) v += h[j] * af_w[o * 32 + j];
        atomicMax(&outMax[(size_t)r1 * 32 + o], f2o(v));
    }
}

// P6: untransform maxf rows < U1, zero rows >= U1; zero coord rows >= U1
__global__ __launch_bounds__(256) void k_final(
    unsigned* __restrict__ out, const unsigned* __restrict__ U1p, int n) {
    int idx = blockIdx.x * 256 + threadIdx.x;
    int n32 = n * 32;
    int U = (int)*U1p;
    if (idx < n32) {
        int row = idx >> 5;
        float f = (row < U) ? o2f(out[idx]) : 0.0f;
        ((float*)out)[idx] = f;
    } else {
        int j = idx - n32;
        if (j < n * 4) {
            int row = j >> 2;
            if (row >= U) ((float*)out)[n32 + j] = 0.0f;
        }
    }
}

// ---------------- host launch ----------------

extern "C" void kernel_launch(void* const* d_in, const int* in_sizes, int n_in,
                              void* d_out, int out_size, void* d_ws, size_t ws_size,
                              hipStream_t stream) {
    const float4* pc = (const float4*)d_in[0];
    const int* ind   = (const int*)d_in[1];
    const float* w05 = (const float*)d_in[2];
    const float* b05 = (const float*)d_in[3];
    const float* ww05 = (const float*)d_in[4];
    const float* wb05 = (const float*)d_in[5];
    const float* w1  = (const float*)d_in[6];
    const float* b1  = (const float*)d_in[7];
    const float* ww1 = (const float*)d_in[8];
    const float* wb1 = (const float*)d_in[9];
    const float* am_w = (const float*)d_in[10];
    const float* am_b = (const float*)d_in[11];
    const float* at_w = (const float*)d_in[12];
    const float* at_b = (const float*)d_in[13];
    const float* af_w = (const float*)d_in[14];
    const float* af_b = (const float*)d_in[15];

    int n = in_sizes[0] / 4;
    int B = in_sizes[1] - 1;

    int nW05 = B * (512 * 512 * 64 / 32);  // words in scale-0.5 bitmask
    int nW1  = B * (256 * 256 * 32 / 32);  // words in scale-1 bitmask
    int nB05 = (nW05 + 2047) / 2048;
    int nB1  = (nW1 + 2047) / 2048;

    size_t off = 0;
    char* base = (char*)d_ws;
    auto take = [&](size_t bytes) -> char* {
        char* p = base + off;
        off = (off + bytes + 255) & ~(size_t)255;
        return p;
    };

    // --- zero-initialized group (single memset) ---
    unsigned* cnt05 = (unsigned*)take((size_t)n * 4);
    unsigned* cnt1  = (unsigned*)take((size_t)n * 4);
    float* s05x = (float*)take((size_t)n * 4);
    float* s05y = (float*)take((size_t)n * 4);
    float* s05z = (float*)take((size_t)n * 4);
    float* s1x  = (float*)take((size_t)n * 4);
    float* s1y  = (float*)take((size_t)n * 4);
    float* s1z  = (float*)take((size_t)n * 4);
    unsigned* mx05 = (unsigned*)take((size_t)n * 16 * 4);
    unsigned* mx1  = (unsigned*)take((size_t)n * 16 * 4);
    unsigned* mask05 = (unsigned*)take((size_t)nW05 * 4);
    unsigned* mask1  = (unsigned*)take((size_t)nW1 * 4);
    size_t zeroBytes = off;

    // --- fully-overwritten group (no init needed) ---
    unsigned* inv05 = (unsigned*)take((size_t)n * 4);
    unsigned* inv1  = (unsigned*)take((size_t)n * 4);
    unsigned* wp05  = (unsigned*)take((size_t)nW05 * 4);
    unsigned* wp1   = (unsigned*)take((size_t)nW1 * 4);
    unsigned* bsum05 = (unsigned*)take((size_t)nB05 * 4);
    unsigned* bpref05 = (unsigned*)take((size_t)nB05 * 4);
    unsigned* bsum1  = (unsigned*)take((size_t)nB1 * 4);
    unsigned* bpref1 = (unsigned*)take((size_t)nB1 * 4);
    unsigned* U1p = (unsigned*)take(4);
    size_t total = off;

    if (ws_size < total) {
        fprintf(stderr, "kernel_launch: ws too small (%zu < %zu)\n", ws_size, total);
        return;
    }

    float* outMaxF = (float*)d_out;                       // [n,32]
    float* outCoord = (float*)d_out + (size_t)n * 32;     // [n,4]
    float* outInv = (float*)d_out + (size_t)n * 36;       // [n]

    hipMemsetAsync(d_ws, 0, zeroBytes, stream);
    hipMemsetAsync(d_out, 0, (size_t)n * 32 * 4, stream);  // maxf region (transformed domain init=0)

    int gpts = (n + 255) / 256;
    k_bits<<<gpts, 256, 0, stream>>>(pc, ind, B, n, mask05, mask1);
    k_chunk<<<nB05, 256, 0, stream>>>(mask05, bsum05, nW05);
    k_chunk<<<nB1, 256, 0, stream>>>(mask1, bsum1, nW1);
    k_scan<<<1, 1024, 0, stream>>>(bsum05, bpref05, nullptr, nB05);
    k_scan<<<1, 1024, 0, stream>>>(bsum1, bpref1, U1p, nB1);
    k_wpref<<<nB05, 256, 0, stream>>>(mask05, bpref05, wp05, nW05);
    k_wpref<<<nB1, 256, 0, stream>>>(mask1, bpref1, wp1, nW1);
    k_rank<<<gpts, 256, 0, stream>>>(pc, ind, B, n, mask05, wp05, mask1, wp1,
                                     inv05, inv1,
                                     cnt05, s05x, s05y, s05z,
                                     cnt1, s1x, s1y, s1z,
                                     outCoord, outInv);
    k_vfemax<<<gpts, 256, 0, stream>>>(pc, ind, B, n, inv05, inv1,
                                       cnt05, s05x, s05y, s05z,
                                       cnt1, s1x, s1y, s1z,
                                       mx05, mx1,
                                       w05, b05, ww05, wb05, w1, b1, ww1, wb1);
    k_agg<<<gpts, 256, 0, stream>>>(pc, ind, B, n, inv05, inv1,
                                    cnt05, s05x, s05y, s05z,
                                    cnt1, s1x, s1y, s1z,
                                    mx05, mx1,
                                    w05, b05, ww05, wb05, w1, b1, ww1, wb1,
                                    am_w, am_b, at_w, at_b, af_w, af_b,
                                    (unsigned*)d_out);
    int tot6 = n * 36;
    k_final<<<(tot6 + 255) / 256, 256, 0, stream>>>((unsigned*)d_out, U1p, n);

    (void)n_in; (void)out_size;
}